// Round 3
// baseline (522.053 us; speedup 1.0000x reference)
//
#include <hip/hip_runtime.h>

typedef unsigned short u16;
typedef unsigned int u32;
typedef __bf16 bf16x8 __attribute__((ext_vector_type(8)));
typedef float f32x4 __attribute__((ext_vector_type(4)));

#define DEVI __device__ __forceinline__

#define BB 16
#define NN 577
#define CC 1024
#define HH 16
#define DD 64
#define BN 9232     // B*N rows
#define PIX 576     // 24*24
#define WW 24
#define CHN 256
#define VROW 584    // padded v^T row length (16B-aligned rows)
#define PSZ (9216 * 256)  // one conv1 partial (elements)

DEVI u16 f2b(float f) {
  u32 u = __builtin_bit_cast(u32, f);
  u32 r = 0x7FFFu + ((u >> 16) & 1u);
  return (u16)((u + r) >> 16);
}

DEVI float b2f(u16 h) { return __builtin_bit_cast(float, (u32)h << 16); }

DEVI bf16x8 ldfrag(const u16* p) {
  uint4 u = *(const uint4*)p;
  return __builtin_bit_cast(bf16x8, u);
}

DEVI f32x4 mfma16(bf16x8 a, bf16x8 b, f32x4 c) {
  return __builtin_amdgcn_mfma_f32_16x16x32_bf16(a, b, c, 0, 0, 0);
}

DEVI void gld_lds16(const u16* g, u16* l) {
  __builtin_amdgcn_global_load_lds((const __attribute__((address_space(1))) void*)g,
                                   (__attribute__((address_space(3))) void*)l, 16, 0, 0);
}

DEVI float gelu_tanh(float v) {
  const float x3 = v * v * v;
  const float t = __expf(1.5957691216057308f * (v + 0.044715f * x3));
  const float th = (t - 1.f) / (t + 1.f);
  return 0.5f * v * (1.f + th);
}

// ---------------- prep: weight bf16 conversion + conv-weight permute + zero page ----
__global__ __launch_bounds__(256) void prep_kernel(
    const float* __restrict__ in_w, const float* __restrict__ out_w,
    const float* __restrict__ c1w, const float* __restrict__ c2w,
    u16* __restrict__ wqkv, u16* __restrict__ wout,
    u16* __restrict__ w1t, u16* __restrict__ w2t, u16* __restrict__ zpad) {
  const int i0 = blockIdx.x * 256 + threadIdx.x;
  const int stride = gridDim.x * 256;
  for (int i = i0; i < 3072 * 1024; i += stride) wqkv[i] = f2b(in_w[i]);
  for (int i = i0; i < 1024 * 1024; i += stride) wout[i] = f2b(out_w[i]);
  // w1t[oc][tap*1024 + c] = conv1_w[oc][c][tap]   (oc<256, c<1024, tap<9)
  for (int i = i0; i < 256 * 9216; i += stride) {
    int oc = i / 9216, rem = i - oc * 9216, tap = rem >> 10, c = rem & 1023;
    w1t[i] = f2b(c1w[(size_t)oc * 9216 + c * 9 + tap]);
  }
  // w2t[oc][tap*256 + c] = conv2_w[oc][c][tap]   (oc<1024, c<256, tap<9)
  for (int i = i0; i < 1024 * 2304; i += stride) {
    int oc = i / 2304, rem = i - oc * 2304, tap = rem >> 8, c = rem & 255;
    w2t[i] = f2b(c2w[(size_t)oc * 2304 + c * 9 + tap]);
  }
  if (i0 < 128) zpad[i0] = 0;
}

// ---------------- LayerNorm (row of 1024), writes bf16; MODE1 also writes cls rows to out
template <int MODE>
__global__ __launch_bounds__(256) void ln_kernel(
    const float* __restrict__ xin, const float* __restrict__ gam,
    const float* __restrict__ bet, u16* __restrict__ yout, float* __restrict__ oextra) {
  __shared__ float sh[8];
  const int row = blockIdx.x;
  const int tid = threadIdx.x;
  const float4 v = ((const float4*)(xin + (size_t)row * CC))[tid];
  float s = v.x + v.y + v.z + v.w;
  float qq = v.x * v.x + v.y * v.y + v.z * v.z + v.w * v.w;
#pragma unroll
  for (int off = 32; off > 0; off >>= 1) {
    s += __shfl_down(s, off);
    qq += __shfl_down(qq, off);
  }
  if ((tid & 63) == 0) { sh[tid >> 6] = s; sh[4 + (tid >> 6)] = qq; }
  __syncthreads();
  s = sh[0] + sh[1] + sh[2] + sh[3];
  qq = sh[4] + sh[5] + sh[6] + sh[7];
  const float mu = s * (1.f / 1024.f);
  const float rstd = rsqrtf(qq * (1.f / 1024.f) - mu * mu + 1e-5f);
  const float4 g4 = ((const float4*)gam)[tid];
  const float4 b4 = ((const float4*)bet)[tid];
  const float o0 = (v.x - mu) * rstd * g4.x + b4.x;
  const float o1 = (v.y - mu) * rstd * g4.y + b4.y;
  const float o2 = (v.z - mu) * rstd * g4.z + b4.z;
  const float o3 = (v.w - mu) * rstd * g4.w + b4.w;
  ushort4 st = make_ushort4(f2b(o0), f2b(o1), f2b(o2), f2b(o3));
  *(ushort4*)(yout + (size_t)row * CC + tid * 4) = st;
  if constexpr (MODE == 1) {
    if (row % NN == NN - 1) {  // cls token row: out = x2 + ln2(x2)
      float4 ov = make_float4(v.x + o0, v.y + o1, v.z + o2, v.w + o3);
      ((float4*)(oextra + (size_t)row * CC))[tid] = ov;
    }
  }
}

// ---------------- 128x128 MFMA GEMM, BK=32, 2-phase double-buffer + XOR swizzle -----
// MODE 0: QKV   A=hb(BNxC)        B=wqkv(3072xC)   -> q,k (b,h,n,d) bf16 + v^T (b,h,d,n)
// MODE 1: PROJ  A=ob(BNxC)        B=wout(1024xC)   -> x2 = acc + bias + res  (f32)
// MODE 3: CONV2 A=gather(f1)      B=w2t(1024x2304) -> out = acc + bias + x2 (f32, row remap)
// MODE 4: CONV1 split-K by tap:   A=gather(y, tap=blockIdx.z) B=w1t slice -> bf16 partial
struct GArgs {
  const u16* A; const u16* Bm; const float* bias; const float* res;
  float* outF; u16* outH; u16* outQ; u16* outK; u16* outV; const u16* zpad;
  int M, K;
};

template <int MODE>
__global__ __launch_bounds__(256) void gemm_kernel(GArgs ag) {
  __shared__ u16 Alds[2][128 * 32];
  __shared__ u16 Blds[2][128 * 32];
  const int tid = threadIdx.x;
  const int w = tid >> 6, l = tid & 63;
  const int wr = w >> 1, wc = w & 1;
  const int lr = l & 15, lg = l >> 4;
  const int m0 = blockIdx.x * 128, n0 = blockIdx.y * 128;
  const int tapz = (MODE == 4) ? blockIdx.z : 0;
  // staging geometry: lane covers row rA (relative), 16B chunk cbs (XOR-swizzled so
  // the linear gld_lds dest holds LDS[row][c'] = global[row][c' ^ ((row>>1)&3)]
  const int rA = w * 16 + (l >> 2);
  const int cbs = ((l & 3) ^ ((l >> 3) & 3)) * 8;

  auto stage = [&](int buf, int k0) {
#pragma unroll
    for (int c = 0; c < 2; ++c) {
      const int r = c * 64 + rA;
      const u16* asrc;
      if constexpr (MODE <= 1) {
        int m = m0 + r;
        m = m < ag.M ? m : ag.M - 1;
        asrc = ag.A + (size_t)m * ag.K + (k0 + cbs);
      } else {
        const int m = m0 + r;
        const int b = m / PIX, p = m - b * PIX;
        const int py = p / WW, px = p - py * WW;
        constexpr int CKc = (MODE == 3) ? 256 : 1024;
        const int tap = (MODE == 4) ? tapz : (k0 / CKc);
        const int c0 = (MODE == 4) ? k0 : (k0 - tap * CKc);
        const int py2 = py + (tap / 3) - 1, px2 = px + (tap % 3) - 1;
        if ((u32)py2 < (u32)WW && (u32)px2 < (u32)WW) {
          if constexpr (MODE == 4)
            asrc = ag.A + ((size_t)(b * NN + py2 * WW + px2) * CC + c0 + cbs);
          else
            asrc = ag.A + ((size_t)(b * PIX + py2 * WW + px2) * CHN + c0 + cbs);
        } else {
          asrc = ag.zpad + cbs;   // zero page (border)
        }
      }
      gld_lds16(asrc, &Alds[buf][c * 2048 + w * 512]);
      const u16* bsrc;
      if constexpr (MODE == 4)
        bsrc = ag.Bm + (size_t)(n0 + r) * 9216 + (tapz * 1024 + k0 + cbs);
      else
        bsrc = ag.Bm + (size_t)(n0 + r) * ag.K + (k0 + cbs);
      gld_lds16(bsrc, &Blds[buf][c * 2048 + w * 512]);
    }
  };

  f32x4 acc[4][4] = {};
  const int KL = (MODE == 4) ? 1024 : ag.K;
  const int nst = KL >> 5;

  stage(0, 0);
  asm volatile("s_waitcnt vmcnt(0)\n\ts_barrier" ::: "memory");

  const int swz = (lr >> 1) & 3;  // read-side XOR (matches staged permutation)
  int cur = 0;
  for (int kt = 0; kt < nst; ++kt) {
    if (kt + 1 < nst) stage(cur ^ 1, (kt + 1) * 32);
    bf16x8 af[4], bfr[4];
#pragma unroll
    for (int i = 0; i < 4; ++i)
      af[i] = ldfrag(&Alds[cur][(wr * 64 + i * 16 + lr) * 32 + ((lg ^ swz) * 8)]);
#pragma unroll
    for (int i = 0; i < 4; ++i)
      bfr[i] = ldfrag(&Blds[cur][(wc * 64 + i * 16 + lr) * 32 + ((lg ^ swz) * 8)]);
#pragma unroll
    for (int mi = 0; mi < 4; ++mi)
#pragma unroll
      for (int ni = 0; ni < 4; ++ni) acc[mi][ni] = mfma16(af[mi], bfr[ni], acc[mi][ni]);
    asm volatile("s_waitcnt vmcnt(0)\n\ts_barrier" ::: "memory");
    cur ^= 1;
  }

  // epilogue: C row = m0 + wr*64 + mi*16 + lg*4 + r ; col = n0 + wc*64 + ni*16 + lr
#pragma unroll
  for (int mi = 0; mi < 4; ++mi) {
#pragma unroll
    for (int r = 0; r < 4; ++r) {
      const int row = m0 + wr * 64 + mi * 16 + lg * 4 + r;
      if (row >= ag.M) continue;
#pragma unroll
      for (int ni = 0; ni < 4; ++ni) {
        const int col = n0 + wc * 64 + ni * 16 + lr;
        if constexpr (MODE == 4) {
          // bf16 partial, no bias: taps 0..4 -> outH base, taps 5..8 -> outQ base
          u16* pb = (tapz < 5) ? ag.outH : ag.outQ;
          const int tl = (tapz < 5) ? tapz : tapz - 5;
          pb[(size_t)tl * PSZ + (size_t)row * CHN + col] = f2b(acc[mi][ni][r]);
        } else {
          const float v = acc[mi][ni][r] + ag.bias[col];
          if constexpr (MODE == 0) {
            const int which = col >> 10, hd = col & 1023, h = hd >> 6, d = hd & 63;
            const int b = row / NN, n = row - b * NN;
            const u16 us = f2b(v);
            if (which == 0)      ag.outQ[((size_t)(b * 16 + h) * NN + n) * DD + d] = us;
            else if (which == 1) ag.outK[((size_t)(b * 16 + h) * NN + n) * DD + d] = us;
            else                 ag.outV[((size_t)(b * 16 + h) * DD + d) * VROW + n] = us;
          } else if constexpr (MODE == 1) {
            const size_t idx = (size_t)row * CC + col;
            ag.outF[idx] = v + ag.res[idx];
          } else {
            const int b = row / PIX, p = row - b * PIX;
            const size_t idx = (size_t)(b * NN + p) * CC + col;
            ag.outF[idx] = v + ag.res[idx];
          }
        }
      }
    }
  }
}

// ---------------- conv1 reduce: f1 = gelu(sum of 9 bf16 partials + bias) -> bf16 ----
__global__ __launch_bounds__(256) void gelu_reduce_kernel(
    const u16* __restrict__ pA, const u16* __restrict__ pB,
    const float* __restrict__ bias, u16* __restrict__ f1) {
  const size_t i4 = ((size_t)blockIdx.x * 256 + threadIdx.x) * 4;
  const int col = (int)(i4 & 255);
  float s0 = 0.f, s1 = 0.f, s2 = 0.f, s3 = 0.f;
#pragma unroll
  for (int t = 0; t < 5; ++t) {
    ushort4 u = *(const ushort4*)(pA + (size_t)t * PSZ + i4);
    s0 += b2f(u.x); s1 += b2f(u.y); s2 += b2f(u.z); s3 += b2f(u.w);
  }
#pragma unroll
  for (int t = 0; t < 4; ++t) {
    ushort4 u = *(const ushort4*)(pB + (size_t)t * PSZ + i4);
    s0 += b2f(u.x); s1 += b2f(u.y); s2 += b2f(u.z); s3 += b2f(u.w);
  }
  const float4 b4 = *(const float4*)(bias + col);
  ushort4 st = make_ushort4(f2b(gelu_tanh(s0 + b4.x)), f2b(gelu_tanh(s1 + b4.y)),
                            f2b(gelu_tanh(s2 + b4.z)), f2b(gelu_tanh(s3 + b4.w)));
  *(ushort4*)(f1 + i4) = st;
}

// ---------------- fused flash attention: 4 waves x 16 q-rows, key tiles of 32 ------
__global__ __launch_bounds__(256) void attn_kernel(
    const u16* __restrict__ q, const u16* __restrict__ k,
    const u16* __restrict__ vt, u16* __restrict__ o) {
  __shared__ u16 Plds[4][512];  // per wave: 16 x 32 bf16
  const int tid = threadIdx.x;
  const int w = tid >> 6, l = tid & 63;
  const int lr = l & 15, lg = l >> 4;
  const int bh = blockIdx.y;
  const int b = bh >> 4, h = bh & 15;
  const int qt = blockIdx.x;

  const u16* qp = q + (size_t)bh * NN * DD;
  const u16* kp = k + (size_t)bh * NN * DD;
  const u16* vp = vt + (size_t)bh * DD * VROW;

  const int qrow = qt * 64 + w * 16 + lr;
  const int qrc = qrow < NN ? qrow : NN - 1;
  const bf16x8 qf0 = ldfrag(qp + (size_t)qrc * DD + lg * 8);
  const bf16x8 qf1 = ldfrag(qp + (size_t)qrc * DD + 32 + lg * 8);

  f32x4 oa[4] = {};
  float mrow[4] = {-1e30f, -1e30f, -1e30f, -1e30f};
  float lsum[4] = {0.f, 0.f, 0.f, 0.f};
  const float se = 0.125f * 1.4426950408889634f;  // scale * log2(e)

  u16* pw = Plds[w];

  for (int kt = 0; kt < 19; ++kt) {
    const int kb = kt * 32;
    const int kg0 = kb + lr, kg1 = kb + 16 + lr;
    const int kr0 = kg0 < NN ? kg0 : NN - 1;
    const int kr1 = kg1 < NN ? kg1 : NN - 1;
    const bf16x8 kf00 = ldfrag(kp + (size_t)kr0 * DD + lg * 8);
    const bf16x8 kf01 = ldfrag(kp + (size_t)kr0 * DD + 32 + lg * 8);
    const bf16x8 kf10 = ldfrag(kp + (size_t)kr1 * DD + lg * 8);
    const bf16x8 kf11 = ldfrag(kp + (size_t)kr1 * DD + 32 + lg * 8);
    f32x4 s0 = {}, s1 = {};
    s0 = mfma16(qf0, kf00, s0);
    s0 = mfma16(qf1, kf01, s0);
    s1 = mfma16(qf0, kf10, s1);
    s1 = mfma16(qf1, kf11, s1);
    const bool v0 = kg0 < NN, v1 = kg1 < NN;
    float t0[4], t1[4], pm[4];
#pragma unroll
    for (int r = 0; r < 4; ++r) {
      t0[r] = v0 ? s0[r] * se : -3e38f;
      t1[r] = v1 ? s1[r] * se : -3e38f;
      pm[r] = fmaxf(t0[r], t1[r]);
    }
#pragma unroll
    for (int off = 1; off < 16; off <<= 1) {
#pragma unroll
      for (int r = 0; r < 4; ++r) pm[r] = fmaxf(pm[r], __shfl_xor(pm[r], off));
    }
    float p0[4], p1[4], rs[4];
#pragma unroll
    for (int r = 0; r < 4; ++r) {
      const float mn = fmaxf(mrow[r], pm[r]);
      const float corr = exp2f(mrow[r] - mn);
      mrow[r] = mn;
      p0[r] = exp2f(t0[r] - mn);
      p1[r] = exp2f(t1[r] - mn);
      rs[r] = p0[r] + p1[r];
      lsum[r] *= corr;
#pragma unroll
      for (int g = 0; g < 4; ++g) oa[g][r] *= corr;
    }
#pragma unroll
    for (int off = 1; off < 16; off <<= 1) {
#pragma unroll
      for (int r = 0; r < 4; ++r) rs[r] += __shfl_xor(rs[r], off);
    }
#pragma unroll
    for (int r = 0; r < 4; ++r) lsum[r] += rs[r];
    // P -> LDS (C-layout rows lg*4+r), re-read as A-fragment (row lr, k=8*lg+e)
#pragma unroll
    for (int r = 0; r < 4; ++r) {
      pw[(lg * 4 + r) * 32 + lr] = f2b(p0[r]);
      pw[(lg * 4 + r) * 32 + 16 + lr] = f2b(p1[r]);
    }
    asm volatile("s_waitcnt lgkmcnt(0)" ::: "memory");
    const bf16x8 pf = ldfrag(&pw[lr * 32 + lg * 8]);
#pragma unroll
    for (int g = 0; g < 4; ++g) {
      const bf16x8 vf = ldfrag(vp + (size_t)(g * 16 + lr) * VROW + kb + lg * 8);
      oa[g] = mfma16(pf, vf, oa[g]);
    }
  }
  // write o[b, n, h*64 + d], normalized
  const int nq = qt * 64 + w * 16 + lg * 4;
#pragma unroll
  for (int r = 0; r < 4; ++r) {
    const int n = nq + r;
    if (n >= NN) continue;
    const float inv = 1.0f / lsum[r];
#pragma unroll
    for (int g = 0; g < 4; ++g)
      o[(size_t)(b * NN + n) * CC + h * DD + g * 16 + lr] = f2b(oa[g][r] * inv);
  }
}

// =====================================================================================
extern "C" void kernel_launch(void* const* d_in, const int* in_sizes, int n_in,
                              void* d_out, int out_size, void* d_ws, size_t ws_size,
                              hipStream_t stream) {
  const float* x     = (const float*)d_in[0];
  const float* ln1_g = (const float*)d_in[1];
  const float* ln1_b = (const float*)d_in[2];
  const float* in_w  = (const float*)d_in[3];
  const float* in_b  = (const float*)d_in[4];
  const float* out_w = (const float*)d_in[5];
  const float* out_b = (const float*)d_in[6];
  const float* ln2_g = (const float*)d_in[7];
  const float* ln2_b = (const float*)d_in[8];
  const float* c1w   = (const float*)d_in[9];
  const float* c1b   = (const float*)d_in[10];
  const float* c2w   = (const float*)d_in[11];
  const float* c2b   = (const float*)d_in[12];
  float* out = (float*)d_out;

  char* ws = (char*)d_ws;
  size_t off = 0;
  auto alloc = [&](size_t bytes) {
    void* p = ws + off;
    off += (bytes + 255) & ~(size_t)255;
    return p;
  };
  u16* hb   = (u16*)alloc((size_t)BN * CC * 2);          // LN1 out; attn out; conv1 partials A(0..3)
  u16* wqkv = (u16*)alloc((size_t)3072 * 1024 * 2);      // conv1 partial A(4) tail
  u16* wout = (u16*)alloc((size_t)1024 * 1024 * 2);
  u16* w1t  = (u16*)alloc((size_t)256 * 9216 * 2);
  u16* w2t  = (u16*)alloc((size_t)1024 * 2304 * 2);
  u16* qb   = (u16*)alloc((size_t)256 * NN * DD * 2);    // later reused as y (LN2 out)
  u16* kb   = (u16*)alloc((size_t)256 * NN * DD * 2);    // later reused as f1
  u16* vtb  = (u16*)alloc((size_t)256 * DD * VROW * 2 + 128);  // conv1 partials B(0..3)
  float* x2 = (float*)alloc((size_t)BN * CC * 4);
  u16* zpad = (u16*)alloc(256);
  u16* ob = hb;
  u16* yb = qb;
  u16* f1 = kb;
  u16* pA = hb;
  u16* pB = vtb;

  prep_kernel<<<1024, 256, 0, stream>>>(in_w, out_w, c1w, c2w, wqkv, wout, w1t, w2t, zpad);
  ln_kernel<0><<<BN, 256, 0, stream>>>(x, ln1_g, ln1_b, hb, nullptr);
  {
    GArgs a{hb, wqkv, in_b, nullptr, nullptr, nullptr, qb, kb, vtb, zpad, BN, CC};
    gemm_kernel<0><<<dim3(73, 24), 256, 0, stream>>>(a);
  }
  attn_kernel<<<dim3(10, 256), 256, 0, stream>>>(qb, kb, vtb, ob);
  {
    GArgs a{ob, wout, out_b, x, x2, nullptr, nullptr, nullptr, nullptr, zpad, BN, CC};
    gemm_kernel<1><<<dim3(73, 8), 256, 0, stream>>>(a);
  }
  ln_kernel<1><<<BN, 256, 0, stream>>>(x2, ln2_g, ln2_b, yb, out);
  {
    // conv1 split-K by tap: 72 x 2 x 9 = 1296 blocks, bf16 partials (no bias)
    GArgs a{yb, w1t, c1b, nullptr, nullptr, pA, pB, nullptr, nullptr, zpad, 9216, 9216};
    gemm_kernel<4><<<dim3(72, 2, 9), 256, 0, stream>>>(a);
  }
  gelu_reduce_kernel<<<2304, 256, 0, stream>>>(pA, pB, c1b, f1);
  {
    GArgs a{f1, w2t, c2b, x2, out, nullptr, nullptr, nullptr, nullptr, zpad, 9216, 2304};
    gemm_kernel<3><<<dim3(72, 8), 256, 0, stream>>>(a);
  }
}

// Round 4
// 507.236 us; speedup vs baseline: 1.0292x; 1.0292x over previous
//
#include <hip/hip_runtime.h>

typedef unsigned short u16;
typedef unsigned int u32;
typedef __bf16 bf16x8 __attribute__((ext_vector_type(8)));
typedef float f32x4 __attribute__((ext_vector_type(4)));

#define DEVI __device__ __forceinline__

#define BB 16
#define NN 577
#define CC 1024
#define HH 16
#define DD 64
#define BN 9232     // B*N rows
#define PIX 576     // 24*24
#define WW 24
#define CHN 256
#define VROW 584    // padded v^T row length (16B-aligned rows)
#define PSZ (9216 * 256)  // one conv1 partial (elements)

DEVI u16 f2b(float f) {
  u32 u = __builtin_bit_cast(u32, f);
  u32 r = 0x7FFFu + ((u >> 16) & 1u);
  return (u16)((u + r) >> 16);
}

DEVI float b2f(u16 h) { return __builtin_bit_cast(float, (u32)h << 16); }

DEVI bf16x8 ldfrag(const u16* p) {
  uint4 u = *(const uint4*)p;
  return __builtin_bit_cast(bf16x8, u);
}

DEVI f32x4 mfma16(bf16x8 a, bf16x8 b, f32x4 c) {
  return __builtin_amdgcn_mfma_f32_16x16x32_bf16(a, b, c, 0, 0, 0);
}

DEVI void gld_lds16(const u16* g, u16* l) {
  __builtin_amdgcn_global_load_lds((const __attribute__((address_space(1))) void*)g,
                                   (__attribute__((address_space(3))) void*)l, 16, 0, 0);
}

DEVI float gelu_tanh(float v) {
  const float x3 = v * v * v;
  const float t = __expf(1.5957691216057308f * (v + 0.044715f * x3));
  const float th = (t - 1.f) / (t + 1.f);
  return 0.5f * v * (1.f + th);
}

// ---------------- prep: weight bf16 conversion + conv-weight permute + zero page ----
__global__ __launch_bounds__(256) void prep_kernel(
    const float* __restrict__ in_w, const float* __restrict__ out_w,
    const float* __restrict__ c1w, const float* __restrict__ c2w,
    u16* __restrict__ wqkv, u16* __restrict__ wout,
    u16* __restrict__ w1t, u16* __restrict__ w2t, u16* __restrict__ zpad) {
  const int i0 = blockIdx.x * 256 + threadIdx.x;
  const int stride = gridDim.x * 256;
  for (int i = i0; i < 3072 * 1024; i += stride) wqkv[i] = f2b(in_w[i]);
  for (int i = i0; i < 1024 * 1024; i += stride) wout[i] = f2b(out_w[i]);
  // w1t[oc][tap*1024 + c] = conv1_w[oc][c][tap]   (oc<256, c<1024, tap<9)
  for (int i = i0; i < 256 * 9216; i += stride) {
    int oc = i / 9216, rem = i - oc * 9216, tap = rem >> 10, c = rem & 1023;
    w1t[i] = f2b(c1w[(size_t)oc * 9216 + c * 9 + tap]);
  }
  // w2t[oc][tap*256 + c] = conv2_w[oc][c][tap]   (oc<1024, c<256, tap<9)
  for (int i = i0; i < 1024 * 2304; i += stride) {
    int oc = i / 2304, rem = i - oc * 2304, tap = rem >> 8, c = rem & 255;
    w2t[i] = f2b(c2w[(size_t)oc * 2304 + c * 9 + tap]);
  }
  if (i0 < 128) zpad[i0] = 0;
}

// ---------------- LayerNorm (row of 1024), writes bf16; MODE1 also writes cls rows to out
template <int MODE>
__global__ __launch_bounds__(256) void ln_kernel(
    const float* __restrict__ xin, const float* __restrict__ gam,
    const float* __restrict__ bet, u16* __restrict__ yout, float* __restrict__ oextra) {
  __shared__ float sh[8];
  const int row = blockIdx.x;
  const int tid = threadIdx.x;
  const float4 v = ((const float4*)(xin + (size_t)row * CC))[tid];
  float s = v.x + v.y + v.z + v.w;
  float qq = v.x * v.x + v.y * v.y + v.z * v.z + v.w * v.w;
#pragma unroll
  for (int off = 32; off > 0; off >>= 1) {
    s += __shfl_down(s, off);
    qq += __shfl_down(qq, off);
  }
  if ((tid & 63) == 0) { sh[tid >> 6] = s; sh[4 + (tid >> 6)] = qq; }
  __syncthreads();
  s = sh[0] + sh[1] + sh[2] + sh[3];
  qq = sh[4] + sh[5] + sh[6] + sh[7];
  const float mu = s * (1.f / 1024.f);
  const float rstd = rsqrtf(qq * (1.f / 1024.f) - mu * mu + 1e-5f);
  const float4 g4 = ((const float4*)gam)[tid];
  const float4 b4 = ((const float4*)bet)[tid];
  const float o0 = (v.x - mu) * rstd * g4.x + b4.x;
  const float o1 = (v.y - mu) * rstd * g4.y + b4.y;
  const float o2 = (v.z - mu) * rstd * g4.z + b4.z;
  const float o3 = (v.w - mu) * rstd * g4.w + b4.w;
  ushort4 st = make_ushort4(f2b(o0), f2b(o1), f2b(o2), f2b(o3));
  *(ushort4*)(yout + (size_t)row * CC + tid * 4) = st;
  if constexpr (MODE == 1) {
    if (row % NN == NN - 1) {  // cls token row: out = x2 + ln2(x2)
      float4 ov = make_float4(v.x + o0, v.y + o1, v.z + o2, v.w + o3);
      ((float4*)(oextra + (size_t)row * CC))[tid] = ov;
    }
  }
}

// ---------------- 128x128 MFMA GEMM, BK=32, 2-phase double-buffer + XOR swizzle -----
// MODE 0: QKV   A=hb(BNxC)        B=wqkv(3072xC)   -> q(pre-scaled),k (b,h,n,d) + v^T
// MODE 1: PROJ  A=ob(BNxC)        B=wout(1024xC)   -> x2 = acc + bias + res  (f32)
// MODE 3: CONV2 A=gather(f1)      B=w2t(1024x2304) -> out = acc + bias + x2 (f32, row remap)
// MODE 4: CONV1 split-K by tap:   A=gather(y, tap=blockIdx.z) B=w1t slice -> bf16 partial
struct GArgs {
  const u16* A; const u16* Bm; const float* bias; const float* res;
  float* outF; u16* outH; u16* outQ; u16* outK; u16* outV; const u16* zpad;
  int M, K;
};

template <int MODE>
__global__ __launch_bounds__(256) void gemm_kernel(GArgs ag) {
  __shared__ u16 Alds[2][128 * 32];
  __shared__ u16 Blds[2][128 * 32];
  const int tid = threadIdx.x;
  const int w = tid >> 6, l = tid & 63;
  const int wr = w >> 1, wc = w & 1;
  const int lr = l & 15, lg = l >> 4;
  const int m0 = blockIdx.x * 128, n0 = blockIdx.y * 128;
  const int tapz = (MODE == 4) ? blockIdx.z : 0;
  const int rA = w * 16 + (l >> 2);
  const int cbs = ((l & 3) ^ ((l >> 3) & 3)) * 8;

  auto stage = [&](int buf, int k0) {
#pragma unroll
    for (int c = 0; c < 2; ++c) {
      const int r = c * 64 + rA;
      const u16* asrc;
      if constexpr (MODE <= 1) {
        int m = m0 + r;
        m = m < ag.M ? m : ag.M - 1;
        asrc = ag.A + (size_t)m * ag.K + (k0 + cbs);
      } else {
        const int m = m0 + r;
        const int b = m / PIX, p = m - b * PIX;
        const int py = p / WW, px = p - py * WW;
        constexpr int CKc = (MODE == 3) ? 256 : 1024;
        const int tap = (MODE == 4) ? tapz : (k0 / CKc);
        const int c0 = (MODE == 4) ? k0 : (k0 - tap * CKc);
        const int py2 = py + (tap / 3) - 1, px2 = px + (tap % 3) - 1;
        if ((u32)py2 < (u32)WW && (u32)px2 < (u32)WW) {
          if constexpr (MODE == 4)
            asrc = ag.A + ((size_t)(b * NN + py2 * WW + px2) * CC + c0 + cbs);
          else
            asrc = ag.A + ((size_t)(b * PIX + py2 * WW + px2) * CHN + c0 + cbs);
        } else {
          asrc = ag.zpad + cbs;   // zero page (border)
        }
      }
      gld_lds16(asrc, &Alds[buf][c * 2048 + w * 512]);
      const u16* bsrc;
      if constexpr (MODE == 4)
        bsrc = ag.Bm + (size_t)(n0 + r) * 9216 + (tapz * 1024 + k0 + cbs);
      else
        bsrc = ag.Bm + (size_t)(n0 + r) * ag.K + (k0 + cbs);
      gld_lds16(bsrc, &Blds[buf][c * 2048 + w * 512]);
    }
  };

  f32x4 acc[4][4] = {};
  const int KL = (MODE == 4) ? 1024 : ag.K;
  const int nst = KL >> 5;

  stage(0, 0);
  asm volatile("s_waitcnt vmcnt(0)\n\ts_barrier" ::: "memory");

  const int swz = (lr >> 1) & 3;  // read-side XOR (matches staged permutation)
  int cur = 0;
  for (int kt = 0; kt < nst; ++kt) {
    if (kt + 1 < nst) stage(cur ^ 1, (kt + 1) * 32);
    bf16x8 af[4], bfr[4];
#pragma unroll
    for (int i = 0; i < 4; ++i)
      af[i] = ldfrag(&Alds[cur][(wr * 64 + i * 16 + lr) * 32 + ((lg ^ swz) * 8)]);
#pragma unroll
    for (int i = 0; i < 4; ++i)
      bfr[i] = ldfrag(&Blds[cur][(wc * 64 + i * 16 + lr) * 32 + ((lg ^ swz) * 8)]);
#pragma unroll
    for (int mi = 0; mi < 4; ++mi)
#pragma unroll
      for (int ni = 0; ni < 4; ++ni) acc[mi][ni] = mfma16(af[mi], bfr[ni], acc[mi][ni]);
    asm volatile("s_waitcnt vmcnt(0)\n\ts_barrier" ::: "memory");
    cur ^= 1;
  }

  // epilogue: C row = m0 + wr*64 + mi*16 + lg*4 + r ; col = n0 + wc*64 + ni*16 + lr
#pragma unroll
  for (int mi = 0; mi < 4; ++mi) {
#pragma unroll
    for (int r = 0; r < 4; ++r) {
      const int row = m0 + wr * 64 + mi * 16 + lg * 4 + r;
      if (row >= ag.M) continue;
#pragma unroll
      for (int ni = 0; ni < 4; ++ni) {
        const int col = n0 + wc * 64 + ni * 16 + lr;
        if constexpr (MODE == 4) {
          u16* pb = (tapz < 5) ? ag.outH : ag.outQ;
          const int tl = (tapz < 5) ? tapz : tapz - 5;
          pb[(size_t)tl * PSZ + (size_t)row * CHN + col] = f2b(acc[mi][ni][r]);
        } else {
          const float v = acc[mi][ni][r] + ag.bias[col];
          if constexpr (MODE == 0) {
            const int which = col >> 10, hd = col & 1023, h = hd >> 6, d = hd & 63;
            const int b = row / NN, n = row - b * NN;
            if (which == 0) {
              // fold softmax scale * log2(e) into q
              ag.outQ[((size_t)(b * 16 + h) * NN + n) * DD + d] = f2b(v * 0.18033688011112042f);
            } else if (which == 1) {
              ag.outK[((size_t)(b * 16 + h) * NN + n) * DD + d] = f2b(v);
            } else {
              ag.outV[((size_t)(b * 16 + h) * DD + d) * VROW + n] = f2b(v);
            }
          } else if constexpr (MODE == 1) {
            const size_t idx = (size_t)row * CC + col;
            ag.outF[idx] = v + ag.res[idx];
          } else {
            const int b = row / PIX, p = row - b * PIX;
            const size_t idx = (size_t)(b * NN + p) * CC + col;
            ag.outF[idx] = v + ag.res[idx];
          }
        }
      }
    }
  }
}

// ---------------- conv1 reduce: f1 = gelu(sum of 9 bf16 partials + bias) -> bf16 ----
__global__ __launch_bounds__(256) void gelu_reduce_kernel(
    const u16* __restrict__ pA, const u16* __restrict__ pB,
    const float* __restrict__ bias, u16* __restrict__ f1) {
  const size_t i4 = ((size_t)blockIdx.x * 256 + threadIdx.x) * 4;
  const int col = (int)(i4 & 255);
  float s0 = 0.f, s1 = 0.f, s2 = 0.f, s3 = 0.f;
#pragma unroll
  for (int t = 0; t < 5; ++t) {
    ushort4 u = *(const ushort4*)(pA + (size_t)t * PSZ + i4);
    s0 += b2f(u.x); s1 += b2f(u.y); s2 += b2f(u.z); s3 += b2f(u.w);
  }
#pragma unroll
  for (int t = 0; t < 4; ++t) {
    ushort4 u = *(const ushort4*)(pB + (size_t)t * PSZ + i4);
    s0 += b2f(u.x); s1 += b2f(u.y); s2 += b2f(u.z); s3 += b2f(u.w);
  }
  const float4 b4 = *(const float4*)(bias + col);
  ushort4 st = make_ushort4(f2b(gelu_tanh(s0 + b4.x)), f2b(gelu_tanh(s1 + b4.y)),
                            f2b(gelu_tanh(s2 + b4.z)), f2b(gelu_tanh(s3 + b4.w)));
  *(ushort4*)(f1 + i4) = st;
}

// ---------------- fused flash attention: swapped QK^T, KVBLK=64, defer-max ---------
// 4 waves x 16 q-rows. Lane holds one q-row (q = lr): softmax reduce is in-lane +
// 2 shuffles. P -> LDS (b64 stores) -> A-fragment for PV. O stays C-layout.
__global__ __launch_bounds__(256) void attn_kernel(
    const u16* __restrict__ q, const u16* __restrict__ k,
    const u16* __restrict__ vt, u16* __restrict__ o) {
  __shared__ u16 Plds[4][1024];  // per wave: 2 halves of 16 q-rows x 32 keys bf16
  const int tid = threadIdx.x;
  const int w = tid >> 6, l = tid & 63;
  const int lr = l & 15, lg = l >> 4;
  const int lg4 = lg * 4;
  const int bh = blockIdx.y;
  const int b = bh >> 4, h = bh & 15;
  const int qt = blockIdx.x;

  const u16* qp = q + (size_t)bh * NN * DD;
  const u16* kp = k + (size_t)bh * NN * DD;
  const u16* vp = vt + (size_t)bh * DD * VROW;

  const int qrow = qt * 64 + w * 16 + lr;
  const int qrc = qrow < NN ? qrow : NN - 1;
  const bf16x8 qf0 = ldfrag(qp + (size_t)qrc * DD + lg * 8);
  const bf16x8 qf1 = ldfrag(qp + (size_t)qrc * DD + 32 + lg * 8);

  f32x4 oa[4] = {};
  float mrow = -1e30f;   // per-lane: q-row = lr (duplicated across lg groups)
  float lsum = 0.f;

  u16* pw = Plds[w];

  for (int kt = 0; kt < 10; ++kt) {
    const int kb = kt * 64;
    // K fragments (A-operand): row = key, identical per-lane layout to old code
    bf16x8 kf0[4], kf1[4];
#pragma unroll
    for (int g = 0; g < 4; ++g) {
      int row = kb + g * 16 + lr;
      row = row < NN ? row : NN - 1;
      const u16* krp = kp + (size_t)row * DD;
      kf0[g] = ldfrag(krp + lg * 8);
      kf1[g] = ldfrag(krp + 32 + lg * 8);
    }
    f32x4 s[4] = {};
#pragma unroll
    for (int g = 0; g < 4; ++g) {
      s[g] = mfma16(kf0[g], qf0, s[g]);   // swapped: scores^T, col = q = lr
      s[g] = mfma16(kf1[g], qf1, s[g]);
    }
    // lane's scores: q = lr, key = kb + g*16 + lg4 + r  (16 per lane)
    float t[16];
    if (kt == 9) {
#pragma unroll
      for (int g = 0; g < 4; ++g)
#pragma unroll
        for (int r = 0; r < 4; ++r)
          t[g * 4 + r] = (kb + g * 16 + lg4 + r < NN) ? s[g][r] : -3e38f;
    } else {
#pragma unroll
      for (int g = 0; g < 4; ++g)
#pragma unroll
        for (int r = 0; r < 4; ++r) t[g * 4 + r] = s[g][r];
    }
    float pmax = t[0];
#pragma unroll
    for (int i = 1; i < 16; ++i) pmax = fmaxf(pmax, t[i]);
    pmax = fmaxf(pmax, __shfl_xor(pmax, 16));
    pmax = fmaxf(pmax, __shfl_xor(pmax, 32));
    // defer-max: only rescale when some row's max grew past threshold
    if (!__all(pmax <= mrow + 8.f)) {
      const float mn = fmaxf(mrow, pmax);
      const float corr = exp2f(mrow - mn);
      mrow = mn;
      lsum *= corr;
      float bc[4];
#pragma unroll
      for (int r = 0; r < 4; ++r) bc[r] = __shfl(corr, (l & 48) | (lg4 + r));
#pragma unroll
      for (int g = 0; g < 4; ++g)
#pragma unroll
        for (int r = 0; r < 4; ++r) oa[g][r] *= bc[r];
    }
    float ps[16];
    float rsum = 0.f;
#pragma unroll
    for (int i = 0; i < 16; ++i) { ps[i] = exp2f(t[i] - mrow); rsum += ps[i]; }
    rsum += __shfl_xor(rsum, 16);
    rsum += __shfl_xor(rsum, 32);
    lsum += rsum;
    // P -> LDS: 4 consecutive keys per (g): pack bf16 pairs, one b64 store each
#pragma unroll
    for (int g = 0; g < 4; ++g) {
      u32 w0, w1;
      asm("v_cvt_pk_bf16_f32 %0, %1, %2" : "=v"(w0) : "v"(ps[g * 4 + 0]), "v"(ps[g * 4 + 1]));
      asm("v_cvt_pk_bf16_f32 %0, %1, %2" : "=v"(w1) : "v"(ps[g * 4 + 2]), "v"(ps[g * 4 + 3]));
      const int off = (g >> 1) * 512 + lr * 32 + (g & 1) * 16 + lg4;
      *(uint2*)(&pw[off]) = make_uint2(w0, w1);
    }
    asm volatile("s_waitcnt lgkmcnt(0)" ::: "memory");
    const bf16x8 paf = ldfrag(&pw[lr * 32 + lg * 8]);         // keys kb..kb+31
    const bf16x8 pbf = ldfrag(&pw[512 + lr * 32 + lg * 8]);   // keys kb+32..kb+63
#pragma unroll
    for (int dg = 0; dg < 4; ++dg) {
      const u16* vr = vp + (size_t)(dg * 16 + lr) * VROW + kb;
      oa[dg] = mfma16(paf, ldfrag(vr + lg * 8), oa[dg]);
      oa[dg] = mfma16(pbf, ldfrag(vr + 32 + lg * 8), oa[dg]);
    }
  }
  // write o[b, n, h*64 + d]; lsum lives at lane lr == row -> broadcast
  const int nq = qt * 64 + w * 16 + lg4;
  float linv[4];
#pragma unroll
  for (int r = 0; r < 4; ++r) linv[r] = __shfl(lsum, (l & 48) | (lg4 + r));
#pragma unroll
  for (int r = 0; r < 4; ++r) {
    const int n = nq + r;
    if (n >= NN) continue;
    const float inv = 1.0f / linv[r];
#pragma unroll
    for (int g = 0; g < 4; ++g)
      o[(size_t)(b * NN + n) * CC + h * DD + g * 16 + lr] = f2b(oa[g][r] * inv);
  }
}

// =====================================================================================
extern "C" void kernel_launch(void* const* d_in, const int* in_sizes, int n_in,
                              void* d_out, int out_size, void* d_ws, size_t ws_size,
                              hipStream_t stream) {
  const float* x     = (const float*)d_in[0];
  const float* ln1_g = (const float*)d_in[1];
  const float* ln1_b = (const float*)d_in[2];
  const float* in_w  = (const float*)d_in[3];
  const float* in_b  = (const float*)d_in[4];
  const float* out_w = (const float*)d_in[5];
  const float* out_b = (const float*)d_in[6];
  const float* ln2_g = (const float*)d_in[7];
  const float* ln2_b = (const float*)d_in[8];
  const float* c1w   = (const float*)d_in[9];
  const float* c1b   = (const float*)d_in[10];
  const float* c2w   = (const float*)d_in[11];
  const float* c2b   = (const float*)d_in[12];
  float* out = (float*)d_out;

  char* ws = (char*)d_ws;
  size_t off = 0;
  auto alloc = [&](size_t bytes) {
    void* p = ws + off;
    off += (bytes + 255) & ~(size_t)255;
    return p;
  };
  u16* hb   = (u16*)alloc((size_t)BN * CC * 2);          // LN1 out; attn out; conv1 partials A(0..3)
  u16* wqkv = (u16*)alloc((size_t)3072 * 1024 * 2);      // conv1 partial A(4) tail
  u16* wout = (u16*)alloc((size_t)1024 * 1024 * 2);
  u16* w1t  = (u16*)alloc((size_t)256 * 9216 * 2);
  u16* w2t  = (u16*)alloc((size_t)1024 * 2304 * 2);
  u16* qb   = (u16*)alloc((size_t)256 * NN * DD * 2);    // later reused as y (LN2 out)
  u16* kb   = (u16*)alloc((size_t)256 * NN * DD * 2);    // later reused as f1
  u16* vtb  = (u16*)alloc((size_t)256 * DD * VROW * 2 + 128);  // conv1 partials B(0..3)
  float* x2 = (float*)alloc((size_t)BN * CC * 4);
  u16* zpad = (u16*)alloc(256);
  u16* ob = hb;
  u16* yb = qb;
  u16* f1 = kb;
  u16* pA = hb;
  u16* pB = vtb;

  prep_kernel<<<1024, 256, 0, stream>>>(in_w, out_w, c1w, c2w, wqkv, wout, w1t, w2t, zpad);
  ln_kernel<0><<<BN, 256, 0, stream>>>(x, ln1_g, ln1_b, hb, nullptr);
  {
    GArgs a{hb, wqkv, in_b, nullptr, nullptr, nullptr, qb, kb, vtb, zpad, BN, CC};
    gemm_kernel<0><<<dim3(73, 24), 256, 0, stream>>>(a);
  }
  attn_kernel<<<dim3(10, 256), 256, 0, stream>>>(qb, kb, vtb, ob);
  {
    GArgs a{ob, wout, out_b, x, x2, nullptr, nullptr, nullptr, nullptr, zpad, BN, CC};
    gemm_kernel<1><<<dim3(73, 8), 256, 0, stream>>>(a);
  }
  ln_kernel<1><<<BN, 256, 0, stream>>>(x2, ln2_g, ln2_b, yb, out);
  {
    // conv1 split-K by tap: 72 x 2 x 9 = 1296 blocks, bf16 partials (no bias)
    GArgs a{yb, w1t, c1b, nullptr, nullptr, pA, pB, nullptr, nullptr, zpad, 9216, 9216};
    gemm_kernel<4><<<dim3(72, 2, 9), 256, 0, stream>>>(a);
  }
  gelu_reduce_kernel<<<2304, 256, 0, stream>>>(pA, pB, c1b, f1);
  {
    GArgs a{f1, w2t, c2b, x2, out, nullptr, nullptr, nullptr, nullptr, zpad, 9216, 2304};
    gemm_kernel<3><<<dim3(72, 8), 256, 0, stream>>>(a);
  }
}